// Round 7
// baseline (149.254 us; speedup 1.0000x reference)
//
#include <hip/hip_runtime.h>
#include <hip/hip_bf16.h>
#include <math.h>

#define MDIM 128
#define CDIM 64
#define NKEYS 21844   // sum 4^i, i=1..7
// layer key offsets: c1=0 c2=4 c3=20 c4=84 c5=340 c6=1364 c7=5460

typedef __attribute__((ext_vector_type(8))) __bf16 bf16x8;
typedef __attribute__((ext_vector_type(4))) float f32x4;

__device__ __forceinline__ int depth_of(int n) {
  if (n < 4)    return 0;
  if (n < 20)   return 1;
  if (n < 84)   return 2;
  if (n < 340)  return 3;
  if (n < 1364) return 4;
  if (n < 5460) return 5;
  return 6;
}

// ---------------------------------------------------------------------------
// K1: keys[n][m] = relu(bk[d][m] + dot(states[n][:], Wk[d][m][:]))  -> bf16
// ---------------------------------------------------------------------------
__global__ __launch_bounds__(128) void k_keys(const float* __restrict__ states,
                                              const float* __restrict__ Wk,
                                              const float* __restrict__ bk,
                                              __hip_bfloat16* __restrict__ keys) {
  __shared__ __align__(16) float sS[4][MDIM];
  const int n0 = blockIdx.x * 4;
  const int m  = threadIdx.x;  // 0..127
  for (int idx = m; idx < 4 * MDIM; idx += 128)
    sS[idx >> 7][idx & 127] = states[(size_t)n0 * MDIM + idx];
  __syncthreads();
  const int d = depth_of(n0);
  const float4* wrow = (const float4*)(Wk + ((size_t)d * MDIM + m) * MDIM);
  float acc0 = 0.f, acc1 = 0.f, acc2 = 0.f, acc3 = 0.f;
#pragma unroll 8
  for (int kq = 0; kq < MDIM / 4; ++kq) {
    float4 w = wrow[kq];
    float4 a = *(const float4*)&sS[0][kq * 4];
    float4 b = *(const float4*)&sS[1][kq * 4];
    float4 c = *(const float4*)&sS[2][kq * 4];
    float4 e = *(const float4*)&sS[3][kq * 4];
    acc0 += w.x * a.x + w.y * a.y + w.z * a.z + w.w * a.w;
    acc1 += w.x * b.x + w.y * b.y + w.z * b.z + w.w * b.w;
    acc2 += w.x * c.x + w.y * c.y + w.z * c.z + w.w * c.w;
    acc3 += w.x * e.x + w.y * e.y + w.z * e.z + w.w * e.w;
  }
  const float bias = bk[d * MDIM + m];
  keys[(size_t)(n0 + 0) * MDIM + m] = __float2bfloat16(fmaxf(acc0 + bias, 0.f));
  keys[(size_t)(n0 + 1) * MDIM + m] = __float2bfloat16(fmaxf(acc1 + bias, 0.f));
  keys[(size_t)(n0 + 2) * MDIM + m] = __float2bfloat16(fmaxf(acc2 + bias, 0.f));
  keys[(size_t)(n0 + 3) * MDIM + m] = __float2bfloat16(fmaxf(acc3 + bias, 0.f));
}

// ---------------------------------------------------------------------------
// K2: query[b][m] = bq[m] + dot(hidden[b][:64], Wq[m][:64])  -> bf16
// ---------------------------------------------------------------------------
__global__ __launch_bounds__(128) void k_query(const float* __restrict__ hidden,
                                               const float* __restrict__ Wq,
                                               const float* __restrict__ bq,
                                               __hip_bfloat16* __restrict__ query) {
  __shared__ __align__(16) float sH[4][CDIM];
  const int b0 = blockIdx.x * 4;
  const int m  = threadIdx.x;
  for (int idx = m; idx < 4 * CDIM; idx += 128)
    sH[idx >> 6][idx & 63] = hidden[(size_t)b0 * CDIM + idx];
  __syncthreads();
  const float4* wrow = (const float4*)(Wq + (size_t)m * CDIM);
  float acc0 = 0.f, acc1 = 0.f, acc2 = 0.f, acc3 = 0.f;
#pragma unroll
  for (int kq = 0; kq < CDIM / 4; ++kq) {
    float4 w = wrow[kq];
    float4 a = *(const float4*)&sH[0][kq * 4];
    float4 b = *(const float4*)&sH[1][kq * 4];
    float4 c = *(const float4*)&sH[2][kq * 4];
    float4 e = *(const float4*)&sH[3][kq * 4];
    acc0 += w.x * a.x + w.y * a.y + w.z * a.z + w.w * a.w;
    acc1 += w.x * b.x + w.y * b.y + w.z * b.z + w.w * b.w;
    acc2 += w.x * c.x + w.y * c.y + w.z * c.z + w.w * c.w;
    acc3 += w.x * e.x + w.y * e.y + w.z * e.z + w.w * e.w;
  }
  const float bias = bq[m];
  query[(size_t)(b0 + 0) * MDIM + m] = __float2bfloat16(acc0 + bias);
  query[(size_t)(b0 + 1) * MDIM + m] = __float2bfloat16(acc1 + bias);
  query[(size_t)(b0 + 2) * MDIM + m] = __float2bfloat16(acc2 + bias);
  query[(size_t)(b0 + 3) * MDIM + m] = __float2bfloat16(acc3 + bias);
}

// ---------------------------------------------------------------------------
// K3: subtree walker, v7 — BARRIER-FREE, per-wave LDS key staging.
// Wave = one depth-5 subtree (S5) x 32 b. No __syncthreads anywhere:
// each wave stages its own 4KB key tile (4 x 1KB coalesced global loads ->
// regs -> swizzled ds_write at tile end). Intra-wave DS ops are in-order,
// so single-buffer overwrite is safe; global stores are never drained by
// barriers (the old s_waitcnt vmcnt(0) per tile was the r4/r6 limiter).
// Cum chain in registers (shuffle parent gather). d7 output (75% of bytes)
// via per-wave LDS transpose buffer [32 b][64 keys] stride 68, flushed per
// u5-group as 8 stores of 4 x 256B segments.
// ---------------------------------------------------------------------------
#define D7STR 68   // padded row stride (floats)

__device__ __forceinline__ float gather_par(const f32x4 cp, int u, int lane) {
  const int src = u * 16 + (lane & 15);
  const float g0 = __shfl(cp[0], src, 64);
  const float g1 = __shfl(cp[1], src, 64);
  const float g2 = __shfl(cp[2], src, 64);
  const float g3 = __shfl(cp[3], src, 64);
  const int hi = lane >> 4;
  const float p01 = (hi & 1) ? g1 : g0;
  const float p23 = (hi & 1) ? g3 : g2;
  return (hi & 2) ? p23 : p01;
}

__device__ __forceinline__ void stage_write(char* __restrict__ sK,
                                            const float4 (&stg)[4], int lane) {
  const int chunk = lane & 15;
#pragma unroll
  for (int i = 0; i < 4; ++i) {
    const int row = i * 4 + (lane >> 4);
    *reinterpret_cast<float4*>(sK + row * 256 + ((chunk ^ (row & 7)) << 4)) = stg[i];
  }
}

__device__ __forceinline__ void tile_step(
    const char* __restrict__ keyBytes, char* __restrict__ sK, int nextBase,
    const bf16x8 (&qf)[2][4], const f32x4* cumPrev, int u,
    f32x4 (&cumOut)[2], float* __restrict__ oBase, size_t span,
    bool doStore, bool d1store, float* __restrict__ d7dst, int lane) {
  const int c = lane & 15, hi = lane >> 4;

  // issue next-tile staging loads early (4 x 1KB contiguous per wave)
  float4 stg[4];
  if (nextBase >= 0) {
    const char* g = keyBytes + (size_t)nextBase * 256 + lane * 16;
#pragma unroll
    for (int i = 0; i < 4; ++i)
      stg[i] = *reinterpret_cast<const float4*>(g + i * 1024);
  }

  // A-frags from swizzled per-wave LDS tile
  bf16x8 af[4];
#pragma unroll
  for (int kf = 0; kf < 4; ++kf)
    af[kf] = *reinterpret_cast<const bf16x8*>(
        sK + c * 256 + (((kf * 4 + hi) ^ (c & 7)) << 4));

#pragma unroll
  for (int bt = 0; bt < 2; ++bt) {
    f32x4 acc = {};
    acc = __builtin_amdgcn_mfma_f32_16x16x32_bf16(af[0], qf[bt][0], acc, 0, 0, 0);
    acc = __builtin_amdgcn_mfma_f32_16x16x32_bf16(af[1], qf[bt][1], acc, 0, 0, 0);
    acc = __builtin_amdgcn_mfma_f32_16x16x32_bf16(af[2], qf[bt][2], acc, 0, 0, 0);
    acc = __builtin_amdgcn_mfma_f32_16x16x32_bf16(af[3], qf[bt][3], acc, 0, 0, 0);
    const float mx  = fmaxf(fmaxf(acc[0], acc[1]), fmaxf(acc[2], acc[3]));
    const float lse = mx + __logf(__expf(acc[0] - mx) + __expf(acc[1] - mx) +
                                  __expf(acc[2] - mx) + __expf(acc[3] - mx));
    float par = 0.f;
    if (cumPrev) par = gather_par(cumPrev[bt], u, lane);
    f32x4 cm;
    cm[0] = acc[0] - lse + par;
    cm[1] = acc[1] - lse + par;
    cm[2] = acc[2] - lse + par;
    cm[3] = acc[3] - lse + par;
    cumOut[bt] = cm;
    if (d7dst) {
      *reinterpret_cast<f32x4*>(d7dst + (bt * 16 + c) * D7STR) = cm;
    } else if (doStore && (!d1store || hi == 0)) {
      float4 o;
      o.x = cm[0]; o.y = cm[1]; o.z = cm[2]; o.w = cm[3];
      *reinterpret_cast<float4*>(oBase + (size_t)(bt * 16 + c) * span + hi * 4) = o;
    }
  }

  // publish staged tile into this wave's buffer (in-order DS pipe: all
  // frag reads above complete first; no barrier needed)
  if (nextBase >= 0) stage_write(sK, stg, lane);
}

__global__ __launch_bounds__(256) void k_tree(const __hip_bfloat16* __restrict__ keys,
                                              const __hip_bfloat16* __restrict__ query,
                                              float* __restrict__ out, int B) {
  __shared__ __align__(16) float sKeys[4][1024];      // per-wave 4KB key tile
  __shared__ __align__(16) float sD7[4][32 * D7STR];  // per-wave d7 transpose buf

  const int tid  = threadIdx.x;
  const int lane = tid & 63;
  const int w    = tid >> 6;
  const int c    = lane & 15, hi = lane >> 4;

  const int S5  = blockIdx.x & 63;        // depth-5 subtree (XCD = S5%8)
  const int bg  = blockIdx.x >> 6;        // batch group (128 b per block)
  const int T4  = S5 >> 2;
  const int T3  = S5 >> 4;
  const int b0w = bg * 128 + w * 32;      // wave's 32-b base

  const char* keyBytes = reinterpret_cast<const char*>(keys);
  char* sK = reinterpret_cast<char*>(&sKeys[w][0]);

  // query B-frags for both b-tiles (held in regs for all 25 tiles)
  bf16x8 qf[2][4];
#pragma unroll
  for (int bt = 0; bt < 2; ++bt) {
    const __hip_bfloat16* qrow = query + (size_t)(b0w + bt * 16 + c) * MDIM;
#pragma unroll
    for (int kf = 0; kf < 4; ++kf)
      qf[bt][kf] = *reinterpret_cast<const bf16x8*>(qrow + kf * 32 + hi * 8);
  }

  // prologue: stage tile 0 (key base 0) into this wave's buffer
  {
    float4 stg[4];
    const char* g = keyBytes + lane * 16;
#pragma unroll
    for (int i = 0; i < 4; ++i)
      stg[i] = *reinterpret_cast<const float4*>(g + i * 1024);
    stage_write(sK, stg, lane);
  }

  f32x4 c1[2], c2[2], c3[2], c4[2], c5[2], c6[2], c7[2];
  float* d7w  = &sD7[w][0];
  float* out7 = out + (size_t)5460 * B + (size_t)b0w * 16384;

  // d1 (keys 0..15; quad hi==0 = real d1 nodes)
  tile_step(keyBytes, sK, 4, qf, nullptr, 0, c1,
            out + (size_t)b0w * 4, 4, S5 == 0, true, nullptr, lane);
  // d2 (keys 4..19)
  tile_step(keyBytes, sK, 20 + 16 * T3, qf, c1, 0, c2,
            out + (size_t)4 * B + (size_t)b0w * 16, 16, S5 == 0, false, nullptr, lane);
  // d3 (tile T3)
  tile_step(keyBytes, sK, 84 + 16 * T4, qf, c2, T3, c3,
            out + (size_t)20 * B + (size_t)b0w * 64 + 16 * T3, 64,
            (S5 & 15) == 0, false, nullptr, lane);
  // d4 (tile T4)
  tile_step(keyBytes, sK, 340 + 16 * S5, qf, c3, T4 & 3, c4,
            out + (size_t)84 * B + (size_t)b0w * 256 + 16 * T4, 256,
            (S5 & 3) == 0, false, nullptr, lane);
  // d5 (tile S5); next = first d6 tile
  tile_step(keyBytes, sK, 1364 + 16 * (4 * S5), qf, c4, S5 & 3, c5,
            out + (size_t)340 * B + (size_t)b0w * 1024 + 16 * S5, 1024,
            true, false, nullptr, lane);

#pragma unroll
  for (int u5 = 0; u5 < 4; ++u5) {
    const int T6 = 4 * S5 + u5;
    // d6 tile T6; next = its first d7 child
    tile_step(keyBytes, sK, 5460 + 16 * (4 * T6), qf, c5, u5, c6,
              out + (size_t)1364 * B + (size_t)b0w * 4096 + 16 * T6, 4096,
              true, false, nullptr, lane);
#pragma unroll
    for (int u6 = 0; u6 < 4; ++u6) {
      const int T7 = 4 * T6 + u6;
      int nb;
      if (u6 < 3)      nb = 5460 + 16 * (T7 + 1);
      else if (u5 < 3) nb = 1364 + 16 * (4 * S5 + u5 + 1);
      else             nb = -1;
      tile_step(keyBytes, sK, nb, qf, c6, u6, c7,
                nullptr, 0, false, false, d7w + u6 * 16 + hi * 4, lane);
    }
    // flush d7 u5-group: 32 b-rows x 64 keys; 8 instrs x 4 x 256B segments
#pragma unroll
    for (int j = 0; j < 8; ++j) {
      const int r = j * 4 + hi;
      f32x4 v = *reinterpret_cast<const f32x4*>(d7w + r * D7STR + c * 4);
      float4 o;
      o.x = v[0]; o.y = v[1]; o.z = v[2]; o.w = v[3];
      *reinterpret_cast<float4*>(out7 + (size_t)r * 16384 + 64 * T6 + c * 4) = o;
    }
  }
}

// ---------------------------------------------------------------------------
extern "C" void kernel_launch(void* const* d_in, const int* in_sizes, int n_in,
                              void* d_out, int out_size, void* d_ws, size_t ws_size,
                              hipStream_t stream) {
  const float* hidden = (const float*)d_in[0];
  const float* Wq     = (const float*)d_in[1];
  const float* bq     = (const float*)d_in[2];
  const float* states = (const float*)d_in[3];
  const float* Wk     = (const float*)d_in[4];
  const float* bk     = (const float*)d_in[5];
  float* out = (float*)d_out;
  const int B = in_sizes[0] / CDIM;  // 4096

  __hip_bfloat16* keys  = (__hip_bfloat16*)d_ws;        // NKEYS*128 bf16 = 5.6 MB
  __hip_bfloat16* query = keys + (size_t)NKEYS * MDIM;  // B*128 bf16 = 1 MB

  k_keys<<<NKEYS / 4, 128, 0, stream>>>(states, Wk, bk, keys);
  k_query<<<B / 4, 128, 0, stream>>>(hidden, Wq, bq, query);

  // grid: subtree-fastest (XCD pinning): 64 subtrees x B/128 batch groups
  k_tree<<<(B / 128) * 64, 256, 0, stream>>>(keys, query, out, B);
}

// Round 8
// 144.188 us; speedup vs baseline: 1.0351x; 1.0351x over previous
//
#include <hip/hip_runtime.h>
#include <hip/hip_bf16.h>
#include <math.h>

#define MDIM 128
#define CDIM 64
#define NKEYS 21844   // sum 4^i, i=1..7
// layer key offsets: c1=0 c2=4 c3=20 c4=84 c5=340 c6=1364 c7=5460

typedef __attribute__((ext_vector_type(8))) __bf16 bf16x8;
typedef __attribute__((ext_vector_type(4))) float f32x4;

// ---------------------------------------------------------------------------
// K0: convert Wk (7x128x128 f32) -> bf16 once.
// ---------------------------------------------------------------------------
__global__ __launch_bounds__(256) void k_cvtw(const float* __restrict__ Wk,
                                              __hip_bfloat16* __restrict__ wkb) {
  const int i = blockIdx.x * 256 + threadIdx.x;   // one float4 per thread
  float4 v = *reinterpret_cast<const float4*>(Wk + (size_t)i * 4);
  __hip_bfloat16 h[4];
  h[0] = __float2bfloat16(v.x); h[1] = __float2bfloat16(v.y);
  h[2] = __float2bfloat16(v.z); h[3] = __float2bfloat16(v.w);
  unsigned long long bits;
  __builtin_memcpy(&bits, h, 8);
  *reinterpret_cast<unsigned long long*>(wkb + (size_t)i * 4) = bits;
}

// ---------------------------------------------------------------------------
// K1: keys via MFMA. One wave per 16 keys (one depth): D = Wk[d] * states^T.
// A = Wk rows (outs), B = states rows (keys): D row = out m = 4*hi+reg (+16ct),
// D col = key = lane&15. Depth-tile table: tiles/depth {1,1,4,16,64,256,1024}.
// ---------------------------------------------------------------------------
__global__ __launch_bounds__(64) void k_keys_mfma(const float* __restrict__ states,
                                                  const __hip_bfloat16* __restrict__ wkb,
                                                  const float* __restrict__ bk,
                                                  __hip_bfloat16* __restrict__ keys) {
  const int lane = threadIdx.x;
  const int c = lane & 15, hi = lane >> 4;
  int blk = blockIdx.x, d, t;
  if      (blk < 2)   { d = blk; t = 0; }
  else if (blk < 6)   { d = 2; t = blk - 2; }
  else if (blk < 22)  { d = 3; t = blk - 6; }
  else if (blk < 86)  { d = 4; t = blk - 22; }
  else if (blk < 342) { d = 5; t = blk - 86; }
  else                { d = 6; t = blk - 342; }
  const int cumArr[7] = {0, 4, 20, 84, 340, 1364, 5460};
  const int k0 = cumArr[d] + 16 * t;

  // B-frags: states rows (keys), f32 -> bf16 inline
  bf16x8 sb[4];
  const float* srow = states + (size_t)(k0 + c) * MDIM;
#pragma unroll
  for (int kf = 0; kf < 4; ++kf) {
    float4 a = *reinterpret_cast<const float4*>(srow + kf * 32 + hi * 8);
    float4 b = *reinterpret_cast<const float4*>(srow + kf * 32 + hi * 8 + 4);
    bf16x8 v;
    v[0] = (__bf16)a.x; v[1] = (__bf16)a.y; v[2] = (__bf16)a.z; v[3] = (__bf16)a.w;
    v[4] = (__bf16)b.x; v[5] = (__bf16)b.y; v[6] = (__bf16)b.z; v[7] = (__bf16)b.w;
    sb[kf] = v;
  }

  const __hip_bfloat16* wkd = wkb + (size_t)d * MDIM * MDIM;
  const float* bkd = bk + d * MDIM;
  const bool valid = (d > 0) || (c < 4);   // d1 tile: only keys 0..3 are depth-1

#pragma unroll
  for (int ct = 0; ct < 8; ++ct) {
    bf16x8 aw[4];
    const __hip_bfloat16* wrow = wkd + (size_t)(ct * 16 + c) * MDIM;
#pragma unroll
    for (int kf = 0; kf < 4; ++kf)
      aw[kf] = *reinterpret_cast<const bf16x8*>(wrow + kf * 32 + hi * 8);
    f32x4 acc = {};
#pragma unroll
    for (int kf = 0; kf < 4; ++kf)
      acc = __builtin_amdgcn_mfma_f32_16x16x32_bf16(aw[kf], sb[kf], acc, 0, 0, 0);
    float4 bias = *reinterpret_cast<const float4*>(bkd + ct * 16 + hi * 4);
    __hip_bfloat16 hv[4];
    hv[0] = __float2bfloat16(fmaxf(acc[0] + bias.x, 0.f));
    hv[1] = __float2bfloat16(fmaxf(acc[1] + bias.y, 0.f));
    hv[2] = __float2bfloat16(fmaxf(acc[2] + bias.z, 0.f));
    hv[3] = __float2bfloat16(fmaxf(acc[3] + bias.w, 0.f));
    if (valid) {
      unsigned long long bits;
      __builtin_memcpy(&bits, hv, 8);
      *reinterpret_cast<unsigned long long*>(
          keys + (size_t)(k0 + c) * MDIM + ct * 16 + 4 * hi) = bits;
    }
  }
}

// ---------------------------------------------------------------------------
// K2: query[b][m] = bq[m] + dot(hidden[b][:64], Wq[m][:64])  -> bf16
// ---------------------------------------------------------------------------
__global__ __launch_bounds__(128) void k_query(const float* __restrict__ hidden,
                                               const float* __restrict__ Wq,
                                               const float* __restrict__ bq,
                                               __hip_bfloat16* __restrict__ query) {
  __shared__ __align__(16) float sH[4][CDIM];
  const int b0 = blockIdx.x * 4;
  const int m  = threadIdx.x;
  for (int idx = m; idx < 4 * CDIM; idx += 128)
    sH[idx >> 6][idx & 63] = hidden[(size_t)b0 * CDIM + idx];
  __syncthreads();
  const float4* wrow = (const float4*)(Wq + (size_t)m * CDIM);
  float acc0 = 0.f, acc1 = 0.f, acc2 = 0.f, acc3 = 0.f;
#pragma unroll
  for (int kq = 0; kq < CDIM / 4; ++kq) {
    float4 w = wrow[kq];
    float4 a = *(const float4*)&sH[0][kq * 4];
    float4 b = *(const float4*)&sH[1][kq * 4];
    float4 c = *(const float4*)&sH[2][kq * 4];
    float4 e = *(const float4*)&sH[3][kq * 4];
    acc0 += w.x * a.x + w.y * a.y + w.z * a.z + w.w * a.w;
    acc1 += w.x * b.x + w.y * b.y + w.z * b.z + w.w * b.w;
    acc2 += w.x * c.x + w.y * c.y + w.z * c.z + w.w * c.w;
    acc3 += w.x * e.x + w.y * e.y + w.z * e.z + w.w * e.w;
  }
  const float bias = bq[m];
  query[(size_t)(b0 + 0) * MDIM + m] = __float2bfloat16(acc0 + bias);
  query[(size_t)(b0 + 1) * MDIM + m] = __float2bfloat16(acc1 + bias);
  query[(size_t)(b0 + 2) * MDIM + m] = __float2bfloat16(acc2 + bias);
  query[(size_t)(b0 + 3) * MDIM + m] = __float2bfloat16(acc3 + bias);
}

// ---------------------------------------------------------------------------
// K3: subtree walker, v8 — chunked subtrees + 1KB-per-instruction d7 flush.
// Block = 4 waves x 64 b x 4 consecutive depth-5 subtrees (chunk=blockIdx&15).
// Wave = 16 b. Keys staged block-shared (dbuf, swizzled, 1 barrier/tile).
// Cum chain in regs (shuffle parent gather). d7: per-wave LDS buffer holds a
// FULL subtree (16 b x 256 keys, stride 260, XOR-swizzled pos = kq^((b&3)<<2));
// flush = 16 instrs, each one b-row of 1KB CONTIGUOUS (lane perm folds into
// the global address; same segment set -> full coalescing). Consecutive
// subtrees extend each b-row's run to 4KB. Grid chunk-fastest: XCD = chunk%8
// pins 2 chunks' keys (~700KB) per XCD L2.
// ---------------------------------------------------------------------------
__device__ __forceinline__ float gather_par(const f32x4 cp, int u, int lane) {
  const int src = u * 16 + (lane & 15);
  const float g0 = __shfl(cp[0], src, 64);
  const float g1 = __shfl(cp[1], src, 64);
  const float g2 = __shfl(cp[2], src, 64);
  const float g3 = __shfl(cp[3], src, 64);
  const int hi = lane >> 4;
  const float p01 = (hi & 1) ? g1 : g0;
  const float p23 = (hi & 1) ? g3 : g2;
  return (hi & 2) ? p23 : p01;
}

__device__ __forceinline__ void tile_step(
    const char* __restrict__ gsrc, char* __restrict__ sdst0,
    const char* __restrict__ sKB, int& sbuf, int nextBase,
    const bf16x8 (&qf)[4], const f32x4* cumPrev, int u, f32x4& cumOut,
    float* __restrict__ oPtr, size_t span, bool doStore, bool d1mask,
    float* __restrict__ d7row, int tt, int lane) {
  const int c = lane & 15, hi = lane >> 4;

  // stage next key tile into regs (1 float4/thread; hides under compute)
  float4 stg;
  if (nextBase >= 0)
    stg = *reinterpret_cast<const float4*>(gsrc + (size_t)nextBase * 256);

  // A-frags from swizzled shared LDS tile
  bf16x8 af[4];
#pragma unroll
  for (int kf = 0; kf < 4; ++kf)
    af[kf] = *reinterpret_cast<const bf16x8*>(
        sKB + sbuf * 4096 + c * 256 + (((kf * 4 + hi) ^ (c & 7)) << 4));

  f32x4 acc = {};
  acc = __builtin_amdgcn_mfma_f32_16x16x32_bf16(af[0], qf[0], acc, 0, 0, 0);
  acc = __builtin_amdgcn_mfma_f32_16x16x32_bf16(af[1], qf[1], acc, 0, 0, 0);
  acc = __builtin_amdgcn_mfma_f32_16x16x32_bf16(af[2], qf[2], acc, 0, 0, 0);
  acc = __builtin_amdgcn_mfma_f32_16x16x32_bf16(af[3], qf[3], acc, 0, 0, 0);

  const float mx  = fmaxf(fmaxf(acc[0], acc[1]), fmaxf(acc[2], acc[3]));
  const float lse = mx + __logf(__expf(acc[0] - mx) + __expf(acc[1] - mx) +
                                __expf(acc[2] - mx) + __expf(acc[3] - mx));
  float par = 0.f;
  if (cumPrev) par = gather_par(*cumPrev, u, lane);
  f32x4 cm;
  cm[0] = acc[0] - lse + par;
  cm[1] = acc[1] - lse + par;
  cm[2] = acc[2] - lse + par;
  cm[3] = acc[3] - lse + par;
  cumOut = cm;

  if (d7row) {
    // pos = kq ^ ((b&3)<<2), kq = tt*4 + hi  (involution; 4-way max on write)
    const int pos = ((tt ^ (c & 3)) << 2) | hi;
    *reinterpret_cast<f32x4*>(d7row + c * 260 + pos * 4) = cm;
  } else if (doStore && (!d1mask || hi == 0)) {
    float4 o;
    o.x = cm[0]; o.y = cm[1]; o.z = cm[2]; o.w = cm[3];
    *reinterpret_cast<float4*>(oPtr + (size_t)c * span + hi * 4) = o;
  }

  if (nextBase >= 0)
    *reinterpret_cast<float4*>(sdst0 + (sbuf ^ 1) * 4096) = stg;
  __syncthreads();
  sbuf ^= 1;
}

__global__ __launch_bounds__(256) void k_tree(const __hip_bfloat16* __restrict__ keys,
                                              const __hip_bfloat16* __restrict__ query,
                                              float* __restrict__ out, int B) {
  __shared__ __align__(16) float sKeys[2][1024];   // 2 x 4KB shared key tiles
  __shared__ __align__(16) float sD7[4][16 * 260]; // per-wave d7 subtree buffer

  const int tid  = threadIdx.x;
  const int lane = tid & 63;
  const int w    = tid >> 6;
  const int c    = lane & 15, hi = lane >> 4;

  const int chunk = blockIdx.x & 15;     // 4-subtree chunk (XCD = chunk%8)
  const int bg    = blockIdx.x >> 4;     // batch group (64 b per block)
  const int T4    = chunk;
  const int T3    = chunk >> 2;
  const int b0w   = bg * 64 + w * 16;    // wave's 16-b base

  const char* keyBytes = reinterpret_cast<const char*>(keys);
  // staging: 256 threads cover 16 rows x 16 chunks of the 4KB tile
  const int srow = tid >> 4, schunk = tid & 15;
  const char* gsrc = keyBytes + (size_t)srow * 256 + schunk * 16;
  char* sdst0 = reinterpret_cast<char*>(&sKeys[0][0]) + srow * 256 +
                ((schunk ^ (srow & 7)) << 4);
  const char* sKB = reinterpret_cast<const char*>(&sKeys[0][0]);

  // query B-frags (held in regs for all tiles)
  bf16x8 qf[4];
  {
    const __hip_bfloat16* qrow = query + (size_t)(b0w + c) * MDIM;
#pragma unroll
    for (int kf = 0; kf < 4; ++kf)
      qf[kf] = *reinterpret_cast<const bf16x8*>(qrow + kf * 32 + hi * 8);
  }

  // prologue: stage d1 tile (key base 0)
  *reinterpret_cast<float4*>(sdst0) = *reinterpret_cast<const float4*>(gsrc);
  __syncthreads();
  int sbuf = 0;

  f32x4 c1, c2, c3, c4, c5, c6, c7;
  float* d7w = &sD7[w][0];

  // d1 (keys 0..15; quad hi==0 = real d1 nodes)
  tile_step(gsrc, sdst0, sKB, sbuf, 4, qf, nullptr, 0, c1,
            out + (size_t)b0w * 4, 4, chunk == 0, true, nullptr, 0, lane);
  // d2 (keys 4..19)
  tile_step(gsrc, sdst0, sKB, sbuf, 20 + 16 * T3, qf, &c1, 0, c2,
            out + (size_t)4 * B + (size_t)b0w * 16, 16, chunk == 0, false,
            nullptr, 0, lane);
  // d3 (tile T3)
  tile_step(gsrc, sdst0, sKB, sbuf, 84 + 16 * T4, qf, &c2, T3, c3,
            out + (size_t)20 * B + (size_t)b0w * 64 + 16 * T3, 64,
            (chunk & 3) == 0, false, nullptr, 0, lane);
  // d4 (tile T4 = chunk)
  tile_step(gsrc, sdst0, sKB, sbuf, 340 + 16 * (4 * chunk), qf, &c3, chunk & 3, c4,
            out + (size_t)84 * B + (size_t)b0w * 256 + 16 * T4, 256,
            true, false, nullptr, 0, lane);

#pragma unroll 1
  for (int u4 = 0; u4 < 4; ++u4) {
    const int S5 = 4 * chunk + u4;
    // d5 (tile S5); next = first d6 tile
    tile_step(gsrc, sdst0, sKB, sbuf, 1364 + 16 * (4 * S5), qf, &c4, u4, c5,
              out + (size_t)340 * B + (size_t)b0w * 1024 + 16 * S5, 1024,
              true, false, nullptr, 0, lane);
#pragma unroll
    for (int u5 = 0; u5 < 4; ++u5) {
      const int T6 = 4 * S5 + u5;
      // d6 tile T6; next = its first d7 child
      tile_step(gsrc, sdst0, sKB, sbuf, 5460 + 16 * (4 * T6), qf, &c5, u5, c6,
                out + (size_t)1364 * B + (size_t)b0w * 4096 + 16 * T6, 4096,
                true, false, nullptr, 0, lane);
#pragma unroll
      for (int u6 = 0; u6 < 4; ++u6) {
        const int T7 = 4 * T6 + u6;
        int nb;
        if (u6 < 3)      nb = 5460 + 16 * (T7 + 1);
        else if (u5 < 3) nb = 1364 + 16 * (T6 + 1);
        else if (u4 < 3) nb = 340 + 16 * (S5 + 1);
        else             nb = -1;
        tile_step(gsrc, sdst0, sKB, sbuf, nb, qf, &c6, u6, c7,
                  nullptr, 0, false, false, d7w, u5 * 4 + u6, lane);
      }
    }
    // flush subtree S5's d7: 16 instrs, each 1 b-row x 1KB contiguous
    {
      float* dst = out + (size_t)5460 * B + (size_t)b0w * 16384 + S5 * 256;
#pragma unroll
      for (int i = 0; i < 16; ++i) {
        f32x4 v = *reinterpret_cast<const f32x4*>(d7w + i * 260 + lane * 4);
        const int kq = lane ^ ((i & 3) << 2);
        float4 o;
        o.x = v[0]; o.y = v[1]; o.z = v[2]; o.w = v[3];
        *reinterpret_cast<float4*>(dst + (size_t)i * 16384 + kq * 4) = o;
      }
    }
  }
}

// ---------------------------------------------------------------------------
extern "C" void kernel_launch(void* const* d_in, const int* in_sizes, int n_in,
                              void* d_out, int out_size, void* d_ws, size_t ws_size,
                              hipStream_t stream) {
  const float* hidden = (const float*)d_in[0];
  const float* Wq     = (const float*)d_in[1];
  const float* bq     = (const float*)d_in[2];
  const float* states = (const float*)d_in[3];
  const float* Wk     = (const float*)d_in[4];
  const float* bk     = (const float*)d_in[5];
  float* out = (float*)d_out;
  const int B = in_sizes[0] / CDIM;  // 4096

  __hip_bfloat16* keys  = (__hip_bfloat16*)d_ws;        // NKEYS*128 bf16
  __hip_bfloat16* query = keys + (size_t)NKEYS * MDIM;  // B*128 bf16
  __hip_bfloat16* wkb   = query + (size_t)B * MDIM;     // 7*128*128 bf16

  k_cvtw<<<(7 * MDIM * MDIM) / (256 * 4), 256, 0, stream>>>(Wk, wkb);
  k_query<<<B / 4, 128, 0, stream>>>(hidden, Wq, bq, query);
  k_keys_mfma<<<1366, 64, 0, stream>>>(states, wkb, bk, keys);

  // grid: chunk-fastest (XCD pinning): 16 chunks x B/64 batch groups
  k_tree<<<(B / 64) * 16, 256, 0, stream>>>(keys, query, out, B);
}